// Round 17
// baseline (82.612 us; speedup 1.0000x reference)
//
#include <hip/hip_runtime.h>
#include <hip/hip_bf16.h>

typedef short bf16x8 __attribute__((ext_vector_type(8)));
typedef float f32x4 __attribute__((ext_vector_type(4)));

typedef __attribute__((address_space(3))) void as3_void;
typedef const __attribute__((address_space(1))) void as1_void;

static constexpr int D = 256;
static constexpr float INV_T = 10.0f;  // 1 / 0.1

__device__ __forceinline__ ushort f2bf(float f) {
  union { float f; unsigned u; } v; v.f = f;
  unsigned r = v.u + 0x7fffu + ((v.u >> 16) & 1u);  // RNE
  return (ushort)(r >> 16);
}

// Kernel 1: L2-normalize rows of images & captions -> bf16; diag logits (fp32).
__global__ __launch_bounds__(256) void normalize_kernel(
    const float* __restrict__ im, const float* __restrict__ cap,
    ushort* __restrict__ imn, ushort* __restrict__ capn,
    float* __restrict__ diag, int N) {
  int tid = blockIdx.x * 256 + threadIdx.x;
  int w = tid >> 6;
  int lane = threadIdx.x & 63;
  if (w >= N) return;
  float4 vi = ((const float4*)(im + (size_t)w * D))[lane];
  float4 vc = ((const float4*)(cap + (size_t)w * D))[lane];
  float ssi = vi.x*vi.x + vi.y*vi.y + vi.z*vi.z + vi.w*vi.w;
  float ssc = vc.x*vc.x + vc.y*vc.y + vc.z*vc.z + vc.w*vc.w;
  #pragma unroll
  for (int m = 1; m < 64; m <<= 1) {
    ssi += __shfl_xor(ssi, m);
    ssc += __shfl_xor(ssc, m);
  }
  float ri = 1.0f / fmaxf(sqrtf(ssi), 1e-12f);
  float rc = 1.0f / fmaxf(sqrtf(ssc), 1e-12f);
  float ax = vi.x*ri, ay = vi.y*ri, az = vi.z*ri, aw = vi.w*ri;
  float cx = vc.x*rc, cy = vc.y*rc, cz = vc.z*rc, cw = vc.w*rc;
  ushort4 ua, uc;
  ua.x = f2bf(ax); ua.y = f2bf(ay); ua.z = f2bf(az); ua.w = f2bf(aw);
  uc.x = f2bf(cx); uc.y = f2bf(cy); uc.z = f2bf(cz); uc.w = f2bf(cw);
  ((ushort4*)(imn + (size_t)w * D))[lane] = ua;
  ((ushort4*)(capn + (size_t)w * D))[lane] = uc;
  float d = ax*cx + ay*cy + az*cz + aw*cw;
  #pragma unroll
  for (int m = 1; m < 64; m <<= 1) d += __shfl_xor(d, m);
  if (lane == 0) diag[w] = d * INV_T;
}

// Kernel 2: barrier-free private-B GEMM at 2 BLOCKS/CU (16 waves, 4/SIMD).
// r16 diagnosis: all schedules latency-bound at 2 waves/SIMD (MFMA 27%,
// VALU 31%, LDS 10%, HBM 7% -- nothing saturated). Fix: LDS 64KB +
// launch_bounds(512,2) (r11/r12-proven: VGPR cap 128, no spill) -> 2 blocks
// co-resident, 4 waves/SIMD of TLP.
// Block = 64 rows x 2048 cols; grid 512 = 128 bm x 4 cg. A resident
// 8x[64][32] (32KB, immutable after the single barrier). Each wave owns a
// private 32-col strip per 256-col tile, private 2x2KB B dbuf (32KB).
// All waits per-wave counted vmcnt; swizzle = verified involution
// (slot(row,u) holds global u^((row>>1)&3); 0 conflicts in r6/r8/r13/r16).
__global__ __launch_bounds__(512, 2) void gemm_exp_kernel(
    const ushort* __restrict__ A, const ushort* __restrict__ Bm,
    float* __restrict__ rowpart, float* __restrict__ colpart, int N) {
  __shared__ ushort As[8][64 * 32];      // 32 KB, immutable after prologue
  __shared__ ushort Bsh[8][2][32 * 32];  // 32 KB, per-wave private dbuf
  int bm = blockIdx.x >> 2;   // 0..127 : rows [bm*64, +64)
  int cg = blockIdx.x & 3;    // 0..3   : cols [cg*2048, +2048)
  int tid = threadIdx.x;
  int lane = tid & 63;
  int wv = tid >> 6;
  int rb = lane & 15;
  int kb = (lane >> 4) * 8;
  int cc = kb ^ (((rb >> 1) & 3) * 8);

  // A staging: 2 thread-halves x 4 rounds cover 8 slices. inner = tid&255:
  // row = inner>>2, unit = inner&3; dest linear inner*16B within slice;
  // source unit pre-swizzled (inner&3)^((inner>>3)&3).
  int inner = tid & 255;
  int chalf = tid >> 8;                 // slices chalf*4 + r
  int ar = inner >> 2;
  int asu = 8 * ((inner & 3) ^ ((inner >> 3) & 3));
  const ushort* agS = A + ((size_t)bm * 64 + ar) * D + asu;

  // B staging (private): load i covers cols i*16+(lane>>2) of the strip;
  // dest linear i*512 + lane*8 elems; source unit (lane&3)^((lane>>3)&3).
  int su = 8 * ((lane & 3) ^ ((lane >> 3) & 3));

  f32x4 acc[4][2];

#define VMWAIT(n) asm volatile("s_waitcnt vmcnt(" #n ")" ::: "memory")
#define LGKM0() asm volatile("s_waitcnt lgkmcnt(0)" ::: "memory")
#define BARRIER() asm volatile("s_barrier" ::: "memory")

#define STAGE_A(r) {                                                         \
    int c_ = chalf * 4 + (r);                                                \
    __builtin_amdgcn_global_load_lds((as1_void*)(agS + c_ * 32),             \
        (as3_void*)(&As[0][0] + c_ * 2048 + inner * 8), 16, 0, 0);           \
  }

#define STAGE_B(P, T, KT) {                                                  \
    const ushort* bp = Bm +                                                  \
        ((size_t)(cg * 2048 + (T) * 256 + wv * 32 + (lane >> 2))) * D +      \
        su + (KT) * 32;                                                      \
    __builtin_amdgcn_global_load_lds((as1_void*)(bp),                        \
        (as3_void*)(&Bsh[wv][P][lane * 8]), 16, 0, 0);                       \
    __builtin_amdgcn_global_load_lds((as1_void*)(bp + (size_t)16 * D),       \
        (as3_void*)(&Bsh[wv][P][512 + lane * 8]), 16, 0, 0);                 \
  }

#define READ_A(AF, KT)                                                      \
  { _Pragma("unroll") for (int mi = 0; mi < 4; ++mi)                        \
      AF[mi] = *(const bf16x8*)(&As[KT][(mi * 16 + rb) * 32 + cc]); }

#define READ_B(BF, P)                                                       \
  { _Pragma("unroll") for (int ni = 0; ni < 2; ++ni)                        \
      BF[ni] = *(const bf16x8*)(&Bsh[wv][P][(ni * 16 + rb) * 32 + cc]); }

#define MFMAS(AF, FB, CZ)                                                   \
  { __builtin_amdgcn_s_setprio(1);                                          \
    _Pragma("unroll") for (int mi = 0; mi < 4; ++mi)                        \
      _Pragma("unroll") for (int ni = 0; ni < 2; ++ni)                      \
        acc[mi][ni] = __builtin_amdgcn_mfma_f32_16x16x32_bf16(              \
            AF[mi], FB[ni],                                                 \
            (CZ) ? (f32x4){0.f, 0.f, 0.f, 0.f} : acc[mi][ni], 0, 0, 0);     \
    __builtin_amdgcn_s_setprio(0); }

#define EPILOGUE(T) {                                                         \
    _Pragma("unroll")                                                         \
    for (int mi = 0; mi < 4; ++mi)                                            \
      _Pragma("unroll")                                                       \
      for (int ni = 0; ni < 2; ++ni)                                          \
        _Pragma("unroll")                                                     \
        for (int r = 0; r < 4; ++r)                                           \
          acc[mi][ni][r] = __expf(acc[mi][ni][r] * INV_T);                    \
    bool sb0 = (lane & 1) != 0, sb1 = (lane & 2) != 0;                        \
    _Pragma("unroll")                                                         \
    for (int mi = 0; mi < 4; ++mi) {                                          \
      float v0 = acc[mi][0][0] + acc[mi][1][0];                               \
      float v1 = acc[mi][0][1] + acc[mi][1][1];                               \
      float v2 = acc[mi][0][2] + acc[mi][1][2];                               \
      float v3 = acc[mi][0][3] + acc[mi][1][3];                               \
      float h0 = (sb0 ? v1 : v0) + __shfl_xor(sb0 ? v0 : v1, 1);              \
      float h1 = (sb0 ? v3 : v2) + __shfl_xor(sb0 ? v2 : v3, 1);              \
      float g  = (sb1 ? h1 : h0) + __shfl_xor(sb1 ? h0 : h1, 2);              \
      g += __shfl_xor(g, 4);                                                  \
      g += __shfl_xor(g, 8);                                                  \
      if ((lane & 12) == 0)                                                   \
        rowpart[(size_t)(cg * 64 + (T) * 8 + wv) * N + bm * 64 + mi * 16 +    \
                (lane >> 4) * 4 + (lane & 3)] = g;                            \
    }                                                                         \
    _Pragma("unroll")                                                         \
    for (int ni = 0; ni < 2; ++ni) {                                          \
      float v = 0.f;                                                          \
      _Pragma("unroll")                                                       \
      for (int mi = 0; mi < 4; ++mi)                                          \
        _Pragma("unroll")                                                     \
        for (int r = 0; r < 4; ++r)                                           \
          v += acc[mi][ni][r];                                                \
      v += __shfl_xor(v, 16); v += __shfl_xor(v, 32);                         \
      if (lane < 16)                                                          \
        colpart[(size_t)bm * N + cg * 2048 + (T) * 256 + wv * 32 + ni * 16 +  \
                lane] = v;                                                    \
    }                                                                         \
  }

  // ---- Prologue: A (4 loads/thread) + own B(tile0, ch0, ch1). ONE barrier.
  STAGE_A(0) STAGE_A(1) STAGE_A(2) STAGE_A(3)
  STAGE_B(0, 0, 0)
  STAGE_B(1, 0, 1)
  VMWAIT(4);    // own A done (leaves ch0, ch1)
  BARRIER();    // all waves' A landed; As immutable hereafter
  VMWAIT(2);    // ch0 done (leaves ch1)
  bf16x8 fbA[2], fbB[2];
  READ_B(fbA, 0)

  for (int T = 0; T < 8; ++T) {
    bf16x8 af[4];
    // body 0: chunk0 (fbA); stage ch2->buf0; drain prior stores via VMWAIT(2).
    LGKM0(); STAGE_B(0, T, 2) READ_A(af, 0) VMWAIT(2); READ_B(fbB, 1)
    MFMAS(af, fbA, 1)
    // body 1..5: chunk k; stage ch(k+2); wait -> ch(k+1) resident.
    LGKM0(); STAGE_B(1, T, 3) READ_A(af, 1) VMWAIT(2); READ_B(fbA, 0)
    MFMAS(af, fbB, 0)
    LGKM0(); STAGE_B(0, T, 4) READ_A(af, 2) VMWAIT(2); READ_B(fbB, 1)
    MFMAS(af, fbA, 0)
    LGKM0(); STAGE_B(1, T, 5) READ_A(af, 3) VMWAIT(2); READ_B(fbA, 0)
    MFMAS(af, fbB, 0)
    LGKM0(); STAGE_B(0, T, 6) READ_A(af, 4) VMWAIT(2); READ_B(fbB, 1)
    MFMAS(af, fbA, 0)
    LGKM0(); STAGE_B(1, T, 7) READ_A(af, 5) VMWAIT(2); READ_B(fbA, 0)
    MFMAS(af, fbB, 0)
    // body 6: chunk6; stage next-tile ch0->buf0; wait -> ch7 resident.
    LGKM0();
    if (T < 7) { STAGE_B(0, T + 1, 0) READ_A(af, 6) VMWAIT(2); }
    else       { READ_A(af, 6) VMWAIT(0); }
    READ_B(fbB, 1)
    MFMAS(af, fbA, 0)
    // body 7: chunk7; stage next-tile ch1->buf1.
    LGKM0();
    if (T < 7) { STAGE_B(1, T + 1, 1) }
    READ_A(af, 7)
    MFMAS(af, fbB, 0)
    // tile end: next-tile ch0,ch1 done; epilogue VALU covers store latency.
    VMWAIT(0);
    EPILOGUE(T)
    READ_B(fbA, 0)   // next tile's ch0 frags
  }
  VMWAIT(0);  // retire final stores

#undef EPILOGUE
#undef MFMAS
#undef READ_B
#undef READ_A
#undef STAGE_B
#undef STAGE_A
#undef VMWAIT
#undef LGKM0
#undef BARRIER
}

// Kernel 3: partial reduction + per-sample loss + atomic accumulate into out.
__global__ __launch_bounds__(256) void reduce_kernel(
    const float* __restrict__ rowpart, const float* __restrict__ colpart,
    const float* __restrict__ diag, float* __restrict__ out,
    int N, int NPr, int NPc) {
  __shared__ float redr[4][64], redc[4][64];
  int w = threadIdx.x >> 6, s = threadIdx.x & 63;
  int i = blockIdx.x * 64 + s;
  float rs = 0.f, cs = 0.f;
  for (int k = w; k < NPr; k += 4) rs += rowpart[(size_t)k * N + i];
  for (int k = w; k < NPc; k += 4) cs += colpart[(size_t)k * N + i];
  redr[w][s] = rs; redc[w][s] = cs;
  __syncthreads();
  if (w == 0) {
    float R = redr[0][s] + redr[1][s] + redr[2][s] + redr[3][s];
    float C = redc[0][s] + redc[1][s] + redc[2][s] + redc[3][s];
    float l = logf(R) + logf(C) - 2.0f * diag[i];
    #pragma unroll
    for (int m = 1; m < 64; m <<= 1) l += __shfl_xor(l, m);
    if (s == 0) atomicAdd(out, l * (0.5f / (float)N));
  }
}

extern "C" void kernel_launch(void* const* d_in, const int* in_sizes, int n_in,
                              void* d_out, int out_size, void* d_ws, size_t ws_size,
                              hipStream_t stream) {
  const float* images = (const float*)d_in[0];
  const float* captions = (const float*)d_in[1];
  int N = in_sizes[0] / D;   // 8192
  int NPr = 256;             // 4 cg x 8 tiles x 8 waves (32-col strips)
  int NPc = 128;             // 128 bm row-panels of 64
  char* w = (char*)d_ws;
  size_t off = 0;
  ushort* imn  = (ushort*)(w + off); off += (size_t)N * D * 2;
  ushort* capn = (ushort*)(w + off); off += (size_t)N * D * 2;
  float* diag    = (float*)(w + off); off += (size_t)N * 4;
  float* rowpart = (float*)(w + off); off += (size_t)NPr * N * 4;
  float* colpart = (float*)(w + off); off += (size_t)NPc * N * 4;
  float* out = (float*)d_out;

  normalize_kernel<<<N / 4, 256, 0, stream>>>(images, captions, imn, capn, diag, N);
  gemm_exp_kernel<<<512, 512, 0, stream>>>(imn, capn, rowpart, colpart, N);
  hipMemsetAsync(out, 0, sizeof(float), stream);
  reduce_kernel<<<N / 64, 256, 0, stream>>>(rowpart, colpart, diag, out, N, NPr, NPc);
}

// Round 18
// 63.686 us; speedup vs baseline: 1.2972x; 1.2972x over previous
//
#include <hip/hip_runtime.h>
#include <hip/hip_bf16.h>
#include <hip/hip_fp8.h>

typedef float f32x4 __attribute__((ext_vector_type(4)));
typedef int i32x4 __attribute__((ext_vector_type(4)));
typedef int i32x8 __attribute__((ext_vector_type(8)));

typedef __attribute__((address_space(3))) void as3_void;
typedef const __attribute__((address_space(1))) void as1_void;

static constexpr int D = 256;
static constexpr float INV_T = 10.0f;  // 1 / 0.1

__device__ __forceinline__ unsigned char f2fp8(float x) {
  __hip_fp8_e4m3 q(x);               // OCP e4m3fn (gfx950)
  return (unsigned char)q.__x;
}

// Kernel 1: L2-normalize rows -> fp8 e4m3; diag logits exact in fp32.
__global__ __launch_bounds__(256) void normalize_kernel(
    const float* __restrict__ im, const float* __restrict__ cap,
    unsigned char* __restrict__ imn, unsigned char* __restrict__ capn,
    float* __restrict__ diag, int N) {
  int tid = blockIdx.x * 256 + threadIdx.x;
  int w = tid >> 6;
  int lane = threadIdx.x & 63;
  if (w >= N) return;
  float4 vi = ((const float4*)(im + (size_t)w * D))[lane];
  float4 vc = ((const float4*)(cap + (size_t)w * D))[lane];
  float ssi = vi.x*vi.x + vi.y*vi.y + vi.z*vi.z + vi.w*vi.w;
  float ssc = vc.x*vc.x + vc.y*vc.y + vc.z*vc.z + vc.w*vc.w;
  #pragma unroll
  for (int m = 1; m < 64; m <<= 1) {
    ssi += __shfl_xor(ssi, m);
    ssc += __shfl_xor(ssc, m);
  }
  float ri = 1.0f / fmaxf(sqrtf(ssi), 1e-12f);
  float rc = 1.0f / fmaxf(sqrtf(ssc), 1e-12f);
  float ax = vi.x*ri, ay = vi.y*ri, az = vi.z*ri, aw = vi.w*ri;
  float cx = vc.x*rc, cy = vc.y*rc, cz = vc.z*rc, cw = vc.w*rc;
  uchar4 ua, uc;
  ua.x = f2fp8(ax); ua.y = f2fp8(ay); ua.z = f2fp8(az); ua.w = f2fp8(aw);
  uc.x = f2fp8(cx); uc.y = f2fp8(cy); uc.z = f2fp8(cz); uc.w = f2fp8(cw);
  ((uchar4*)(imn + (size_t)w * D))[lane] = ua;
  ((uchar4*)(capn + (size_t)w * D))[lane] = uc;
  float d = ax*cx + ay*cy + az*cz + aw*cw;
  #pragma unroll
  for (int m = 1; m < 64; m <<= 1) d += __shfl_xor(d, m);
  if (lane == 0) diag[w] = d * INV_T;
}

// Kernel 2: MX-fp8 GEMM (mfma_scale 16x16x128, scales = 1.0).
// r13 shell: grid 256 (1/CU), block = bm(256 rows) x 4 bn-tiles(256 cols);
// 8 waves 2Mx4N, wave tile 128x64. K=256 fp8:
//   A resident [4 subK][256 row][64B] = 64 KB (immutable after prologue);
//   B per-K-half [2 subK][256 col][64B] = 32 KB x 2 buffers. LDS 128 KB.
// Only 8 compute steps/block (32 MFMA each, K=128 per MFMA = 4x fewer
// instructions than bf16 at 2x rate). Stage-ahead 2 half-steps; counted
// vmcnt(4); stores issued before stages. Swizzle: 16B-unit u stored at
// u ^ (((row>>1)+(row>>3))&3) -- same 2-way/quarter-wave class as r8's
// measured-0-conflict pattern. C/D layout = 16x16 standard (shape-determined,
// m127/m128) -> epilogue identical to r13's verified one.
__global__ __launch_bounds__(512) void gemm_exp_kernel(
    const unsigned char* __restrict__ A, const unsigned char* __restrict__ Bm,
    float* __restrict__ rowpart, float* __restrict__ colpart, int N) {
  __shared__ unsigned char AsF[65536];      // [sub4][row 256][64B]
  __shared__ unsigned char BsF[2][32768];   // [sub2][col 256][64B] each
  int bm = blockIdx.x >> 3;
  int grp = blockIdx.x & 7;
  int tid = threadIdx.x;
  int lane = tid & 63;
  int wv = tid >> 6;
  int wm = wv >> 2;            // rows [wm*128, +128)
  int wn = wv & 3;             // cols [wn*64, +64)
  int rb = lane & 15;
  int kp = lane >> 4;          // k-part 0..3 (32B each)

  f32x4 acc[8][4];

  // staging source offsets: slot s = q*512 + wv*64 + lane covers 16B unit:
  // sub = s>>10, row = (s>>2)&255, u' = s&3, u = u' ^ h2(row).
  int sb = wv * 64 + lane;
  int boff[4];
  #pragma unroll
  for (int q = 0; q < 4; ++q) {
    int s = q * 512 + sb;
    int sub = s >> 10, row = (s >> 2) & 255;
    int u = (s & 3) ^ (((row >> 1) + (row >> 3)) & 3);
    boff[q] = row * 256 + sub * 64 + u * 16;
  }

#define VMWAIT(n) asm volatile("s_waitcnt vmcnt(" #n ")" ::: "memory")
#define LGKM0() asm volatile("s_waitcnt lgkmcnt(0)" ::: "memory")
#define BARRIER() asm volatile("s_barrier" ::: "memory")

#define STAGE_B(P, TILE, KH) {                                               \
    const unsigned char* bsrc_ = Bm + (size_t)(TILE) * 65536 + (KH) * 128;   \
    _Pragma("unroll")                                                        \
    for (int q = 0; q < 4; ++q)                                              \
      __builtin_amdgcn_global_load_lds((as1_void*)(bsrc_ + boff[q]),         \
          (as3_void*)(&BsF[P][q * 8192 + wv * 1024]), 16, 0, 0);             \
  }

#define READ_A8(dst, mi, KH) {                                               \
    int row_ = wm * 128 + (mi) * 16 + rb;                                    \
    int h2_ = ((row_ >> 1) + (row_ >> 3)) & 3;                               \
    const unsigned char* ab_ =                                               \
        &AsF[((KH) * 2 + (kp >> 1)) * 16384 + row_ * 64];                    \
    i32x4 lo_ = *(const i32x4*)(ab_ + ((((kp & 1) * 2 + 0) ^ h2_) << 4));    \
    i32x4 hi_ = *(const i32x4*)(ab_ + ((((kp & 1) * 2 + 1) ^ h2_) << 4));    \
    dst = __builtin_shufflevector(lo_, hi_, 0, 1, 2, 3, 4, 5, 6, 7);         \
  }

#define READ_B8(dst, ni, P) {                                                \
    int col_ = wn * 64 + (ni) * 16 + rb;                                     \
    int h2_ = ((col_ >> 1) + (col_ >> 3)) & 3;                               \
    const unsigned char* bb_ = &BsF[P][(kp >> 1) * 16384 + col_ * 64];       \
    i32x4 lo_ = *(const i32x4*)(bb_ + ((((kp & 1) * 2 + 0) ^ h2_) << 4));    \
    i32x4 hi_ = *(const i32x4*)(bb_ + ((((kp & 1) * 2 + 1) ^ h2_) << 4));    \
    dst = __builtin_shufflevector(lo_, hi_, 0, 1, 2, 3, 4, 5, 6, 7);         \
  }

  // one K-half compute: 4 B-frags + per-mi A-frag, 32 MFMA (K=128 each)
#define COMPUTE(P, KH, CZ) {                                                 \
    i32x8 bfr[4];                                                            \
    READ_B8(bfr[0], 0, P) READ_B8(bfr[1], 1, P)                              \
    READ_B8(bfr[2], 2, P) READ_B8(bfr[3], 3, P)                              \
    _Pragma("unroll")                                                        \
    for (int mi = 0; mi < 8; ++mi) {                                         \
      i32x8 a8;                                                              \
      READ_A8(a8, mi, KH)                                                    \
      __builtin_amdgcn_s_setprio(1);                                         \
      _Pragma("unroll")                                                      \
      for (int ni = 0; ni < 4; ++ni)                                         \
        acc[mi][ni] = __builtin_amdgcn_mfma_scale_f32_16x16x128_f8f6f4(      \
            a8, bfr[ni],                                                     \
            (CZ) ? (f32x4){0.f, 0.f, 0.f, 0.f} : acc[mi][ni],                \
            0, 0, 0, 0x7F7F7F7F, 0, 0x7F7F7F7F);                             \
      __builtin_amdgcn_s_setprio(0);                                         \
    }                                                                        \
    LGKM0();                                                                 \
  }

  // r13-verified epilogue (16x16 C/D layout; packed 4-value butterfly)
#define EPILOGUE(BN) {                                                        \
    _Pragma("unroll")                                                         \
    for (int mi = 0; mi < 8; ++mi)                                            \
      _Pragma("unroll")                                                       \
      for (int ni = 0; ni < 4; ++ni)                                          \
        _Pragma("unroll")                                                     \
        for (int r = 0; r < 4; ++r)                                           \
          acc[mi][ni][r] = __expf(acc[mi][ni][r] * INV_T);                    \
    bool sb0 = (lane & 1) != 0, sb1 = (lane & 2) != 0;                        \
    _Pragma("unroll")                                                         \
    for (int mi = 0; mi < 8; ++mi) {                                          \
      float v0 = acc[mi][0][0] + acc[mi][1][0] + acc[mi][2][0] + acc[mi][3][0]; \
      float v1 = acc[mi][0][1] + acc[mi][1][1] + acc[mi][2][1] + acc[mi][3][1]; \
      float v2 = acc[mi][0][2] + acc[mi][1][2] + acc[mi][2][2] + acc[mi][3][2]; \
      float v3 = acc[mi][0][3] + acc[mi][1][3] + acc[mi][2][3] + acc[mi][3][3]; \
      float h0 = (sb0 ? v1 : v0) + __shfl_xor(sb0 ? v0 : v1, 1);              \
      float h1 = (sb0 ? v3 : v2) + __shfl_xor(sb0 ? v2 : v3, 1);              \
      float g  = (sb1 ? h1 : h0) + __shfl_xor(sb1 ? h0 : h1, 2);              \
      g += __shfl_xor(g, 4);                                                  \
      g += __shfl_xor(g, 8);                                                  \
      if ((lane & 12) == 0)                                                   \
        rowpart[(size_t)((BN) * 4 + wn) * N + bm * 256 + wm * 128 + mi * 16 + \
                (lane >> 4) * 4 + (lane & 3)] = g;                            \
    }                                                                         \
    _Pragma("unroll")                                                         \
    for (int ni = 0; ni < 4; ++ni) {                                          \
      float v = 0.f;                                                          \
      _Pragma("unroll")                                                       \
      for (int mi = 0; mi < 8; ++mi)                                          \
        _Pragma("unroll")                                                     \
        for (int r = 0; r < 4; ++r)                                           \
          v += acc[mi][ni][r];                                                \
      v += __shfl_xor(v, 16); v += __shfl_xor(v, 32);                         \
      if (lane < 16)                                                          \
        colpart[(size_t)(bm * 2 + wm) * N + (BN) * 256 + wn * 64 + ni * 16 +  \
                lane] = v;                                                    \
    }                                                                         \
  }

#define TILE(j) (grp * 4 + (j))

  // ---- Prologue: A (8 loads/thread) + B(tile0, half0, half1)
  #pragma unroll
  for (int q = 0; q < 8; ++q) {
    int s = q * 512 + sb;
    int sub = s >> 10, row = (s >> 2) & 255;
    int u = (s & 3) ^ (((row >> 1) + (row >> 3)) & 3);
    __builtin_amdgcn_global_load_lds(
        (as1_void*)(A + (size_t)bm * 65536 + row * 256 + sub * 64 + u * 16),
        (as3_void*)(&AsF[q * 8192 + wv * 1024]), 16, 0, 0);
  }
  STAGE_B(0, TILE(0), 0)
  STAGE_B(1, TILE(0), 1)
  VMWAIT(4); BARRIER();   // A + half0 resident; half1 (newest 4) in flight

  // 8 half-steps; stage half i+2 into buf i&1 after the barrier frees it.
  COMPUTE(0, 0, 1) BARRIER();               STAGE_B(0, TILE(1), 0) VMWAIT(4); BARRIER();
  COMPUTE(1, 1, 0) BARRIER(); EPILOGUE(TILE(0)) STAGE_B(1, TILE(1), 1) VMWAIT(4); BARRIER();
  COMPUTE(0, 0, 1) BARRIER();               STAGE_B(0, TILE(2), 0) VMWAIT(4); BARRIER();
  COMPUTE(1, 1, 0) BARRIER(); EPILOGUE(TILE(1)) STAGE_B(1, TILE(2), 1) VMWAIT(4); BARRIER();
  COMPUTE(0, 0, 1) BARRIER();               STAGE_B(0, TILE(3), 0) VMWAIT(4); BARRIER();
  COMPUTE(1, 1, 0) BARRIER(); EPILOGUE(TILE(2)) STAGE_B(1, TILE(3), 1) VMWAIT(4); BARRIER();
  COMPUTE(0, 0, 1) BARRIER();               VMWAIT(0); BARRIER();
  COMPUTE(1, 1, 0) EPILOGUE(TILE(3))
  VMWAIT(0);  // retire final stores

#undef TILE
#undef EPILOGUE
#undef COMPUTE
#undef READ_B8
#undef READ_A8
#undef STAGE_B
#undef VMWAIT
#undef LGKM0
#undef BARRIER
}

// Kernel 3: partial reduction + per-sample loss + atomic accumulate into out.
__global__ __launch_bounds__(256) void reduce_kernel(
    const float* __restrict__ rowpart, const float* __restrict__ colpart,
    const float* __restrict__ diag, float* __restrict__ out,
    int N, int NPr, int NPc) {
  __shared__ float redr[4][64], redc[4][64];
  int w = threadIdx.x >> 6, s = threadIdx.x & 63;
  int i = blockIdx.x * 64 + s;
  float rs = 0.f, cs = 0.f;
  for (int k = w; k < NPr; k += 4) rs += rowpart[(size_t)k * N + i];
  for (int k = w; k < NPc; k += 4) cs += colpart[(size_t)k * N + i];
  redr[w][s] = rs; redc[w][s] = cs;
  __syncthreads();
  if (w == 0) {
    float R = redr[0][s] + redr[1][s] + redr[2][s] + redr[3][s];
    float C = redc[0][s] + redc[1][s] + redc[2][s] + redc[3][s];
    float l = logf(R) + logf(C) - 2.0f * diag[i];
    #pragma unroll
    for (int m = 1; m < 64; m <<= 1) l += __shfl_xor(l, m);
    if (s == 0) atomicAdd(out, l * (0.5f / (float)N));
  }
}

extern "C" void kernel_launch(void* const* d_in, const int* in_sizes, int n_in,
                              void* d_out, int out_size, void* d_ws, size_t ws_size,
                              hipStream_t stream) {
  const float* images = (const float*)d_in[0];
  const float* captions = (const float*)d_in[1];
  int N = in_sizes[0] / D;   // 8192
  int NPr = 128;             // 32 bn-tiles x 4 wn
  int NPc = 64;              // 32 bm-blocks x 2 wm
  char* w = (char*)d_ws;
  size_t off = 0;
  unsigned char* imn  = (unsigned char*)(w + off); off += (size_t)N * D;
  unsigned char* capn = (unsigned char*)(w + off); off += (size_t)N * D;
  float* diag    = (float*)(w + off); off += (size_t)N * 4;
  float* rowpart = (float*)(w + off); off += (size_t)NPr * N * 4;
  float* colpart = (float*)(w + off); off += (size_t)NPc * N * 4;
  float* out = (float*)d_out;

  normalize_kernel<<<N / 4, 256, 0, stream>>>(images, captions, imn, capn, diag, N);
  gemm_exp_kernel<<<256, 512, 0, stream>>>(imn, capn, rowpart, colpart, N);
  hipMemsetAsync(out, 0, sizeof(float), stream);
  reduce_kernel<<<N / 64, 256, 0, stream>>>(rowpart, colpart, diag, out, N, NPr, NPc);
}